// Round 11
// baseline (1755.998 us; speedup 1.0000x reference)
//
#include <hip/hip_runtime.h>
#include <hip/hip_cooperative_groups.h>
namespace cg = cooperative_groups;

#define NN 100000
#define EE 1600000
#define DI 128
#define HH 64
#define CO 10
#define PADF 16                             // floats per staged row (64B line)
#define GG 1024
#define BSH 7
#define BNODES 128
#define NB ((NN + BNODES - 1) / BNODES)     // 782
#define TILE 4096
#define NT ((EE + TILE - 1) / TILE)         // 391
#define SN (NB * NT)
#define SCB 1024
#define NSB ((SN + SCB - 1) / SCB)          // 299
#define LPN 4
#define GRID 1536                           // 6 blocks/CU x 256 CUs (co-resident)
#define BT 256

struct GP {
    const float* x; const int* row; const int* col; const int* batch;
    const float* W1; const float* b1; const float* W2; const float* b2;
    const float* W3; const float* b3; const float* Wl; const float* bl;
    float* out;
    float* Wf; float* cvec; float* dinv;
    int* S; int* bsum; unsigned* ebuf; int* srcIdx; int* rowptr;
    float* as_; float* bbuf; int* gstart;
};

// ---------------- P0: tile bucket-histograms + collapsed weights + gstart ----------------
__device__ void ph_front(const GP& p, int* smem) {
    int bid = blockIdx.x, t = threadIdx.x;
    float* smf = (float*)smem;
    for (int tile = bid; tile < NT; tile += GRID) {
        for (int i = t; i < NB; i += BT) smem[i] = 0;
        __syncthreads();
        int base = tile * TILE, end = min(base + TILE, EE);
        for (int e = base + t; e < end; e += BT)
            atomicAdd(&smem[__builtin_nontemporal_load(&p.col[e]) >> BSH], 1);
        __syncthreads();
        for (int i = t; i < NB; i += BT) p.S[i * NT + tile] = smem[i];
        __syncthreads();
    }
    if (bid == GRID - 1) {   // collapsed weights Wf = W1@W2@W3@Wl; c1,c2,c3
        float* M3l = smf; float* M23l = smf + HH * CO;
        for (int i = t; i < HH * CO; i += BT) {
            int r = i / CO, c = i % CO; float s = 0.f;
            for (int k = 0; k < HH; ++k) s += p.W3[r * HH + k] * p.Wl[k * CO + c];
            M3l[i] = s;
        }
        __syncthreads();
        for (int i = t; i < HH * CO; i += BT) {
            int r = i / CO, c = i % CO; float s = 0.f;
            for (int k = 0; k < HH; ++k) s += p.W2[r * HH + k] * M3l[k * CO + c];
            M23l[i] = s;
        }
        __syncthreads();
        for (int i = t; i < DI * CO; i += BT) {
            int r = i / CO, c = i % CO; float s = 0.f;
            for (int k = 0; k < HH; ++k) s += p.W1[r * HH + k] * M23l[k * CO + c];
            p.Wf[i] = s;
        }
        if (t < CO) {
            float s1 = 0.f, s2 = 0.f, s3 = 0.f;
            for (int k = 0; k < HH; ++k) {
                s1 += p.b1[k] * M23l[k * CO + t];
                s2 += p.b2[k] * M3l[k * CO + t];
                s3 += p.b3[k] * p.Wl[k * CO + t];
            }
            p.cvec[t] = s1; p.cvec[CO + t] = s2; p.cvec[2 * CO + t] = s3;
        }
    }
    for (int g = bid * BT + t; g <= GG; g += GRID * BT) {
        int lo = 0, hi = NN;
        while (lo < hi) { int mid = (lo + hi) >> 1; if (p.batch[mid] < g) lo = mid + 1; else hi = mid; }
        p.gstart[g] = lo;
    }
}

// ---------------- P1: scanA (1024 elems per scan-block, 256 thr x 4) ----------------
__device__ void ph_scanA(const GP& p, int* smem) {
    int bid = blockIdx.x, t = threadIdx.x;
    for (int sb = bid; sb < NSB; sb += GRID) {
        int idx0 = sb * SCB + t * 4;
        int v0 = (idx0 < SN) ? p.S[idx0] : 0;
        int v1 = (idx0 + 1 < SN) ? p.S[idx0 + 1] : 0;
        int v2 = (idx0 + 2 < SN) ? p.S[idx0 + 2] : 0;
        int v3 = (idx0 + 3 < SN) ? p.S[idx0 + 3] : 0;
        int l1 = v0, l2 = l1 + v1, l3 = l2 + v2, l4 = l3 + v3;
        smem[t] = l4;
        __syncthreads();
        for (int off = 1; off < BT; off <<= 1) {
            int u = (t >= off) ? smem[t - off] : 0;
            __syncthreads();
            smem[t] += u;
            __syncthreads();
        }
        int excl = smem[t] - l4;
        if (idx0 < SN) p.S[idx0] = excl;
        if (idx0 + 1 < SN) p.S[idx0 + 1] = excl + l1;
        if (idx0 + 2 < SN) p.S[idx0 + 2] = excl + l2;
        if (idx0 + 3 < SN) p.S[idx0 + 3] = excl + l3;
        if (t == BT - 1) p.bsum[sb] = excl + l4;
        __syncthreads();
    }
}

// ---------------- P2: scanC (add block offsets) ----------------
__device__ void ph_scanC(const GP& p, int* smem) {
    int bid = blockIdx.x, t = threadIdx.x;
    for (int sb = bid; sb < NSB; sb += GRID) {
        int partial = 0;
        for (int i = t; i < sb; i += BT) partial += p.bsum[i];
        smem[t] = partial;
        __syncthreads();
        for (int off = BT / 2; off > 0; off >>= 1) {
            if (t < off) smem[t] += smem[t + off];
            __syncthreads();
        }
        int add = smem[0];
        int idx0 = sb * SCB + t * 4;
#pragma unroll
        for (int k = 0; k < 4; ++k) { int id = idx0 + k; if (id < SN) p.S[id] += add; }
        __syncthreads();
    }
}

// ---------------- P3: pscatter (blocks<NT)  ||  xw-unscaled (blocks NT..2NT) ----------------
__device__ void ph_scatter_xw(const GP& p, int* smem) {
    int bid = blockIdx.x, t = threadIdx.x;
    float* smf = (float*)smem;
    if (bid < NT) {
        for (int i = t; i < NB; i += BT) smem[i] = p.S[i * NT + bid];
        __syncthreads();
        int base = bid * TILE, end = min(base + TILE, EE);
        for (int e = base + t; e < end; e += BT) {
            int c = __builtin_nontemporal_load(&p.col[e]);
            int r = __builtin_nontemporal_load(&p.row[e]);
            int pos = atomicAdd(&smem[c >> BSH], 1);
            p.ebuf[pos] = ((unsigned)r << BSH) | (unsigned)(c & (BNODES - 1));
        }
    } else if (bid < 2 * NT) {
        for (int i = t; i < DI * CO; i += BT) smf[i] = p.Wf[i];
        __syncthreads();
        int gid = (bid - NT) * BT + t;
        if (gid < NN) {
            int pr = gid >> 1, c0 = (gid & 1) * 5;
            int n0 = 2 * pr, n1 = n0 + 1;
            float a0[5] = {0, 0, 0, 0, 0}, a1[5] = {0, 0, 0, 0, 0};
            const float4* x0 = (const float4*)(p.x + (size_t)n0 * DI);
            const float4* x1 = (const float4*)(p.x + (size_t)n1 * DI);
#pragma unroll 4
            for (int d4 = 0; d4 < DI / 4; ++d4) {
                float4 u = x0[d4], v = x1[d4];
                const float* w = &smf[d4 * 4 * CO + c0];
#pragma unroll
                for (int c = 0; c < 5; ++c) {
                    float w0 = w[c], w1 = w[CO + c], w2 = w[2 * CO + c], w3 = w[3 * CO + c];
                    a0[c] += u.x * w0 + u.y * w1 + u.z * w2 + u.w * w3;
                    a1[c] += v.x * w0 + v.y * w1 + v.z * w2 + v.w * w3;
                }
            }
            float* r0 = p.as_ + (size_t)n0 * PADF + c0;
            float* r1 = p.as_ + (size_t)n1 * PADF + c0;
#pragma unroll
            for (int c = 0; c < 5; ++c) { r0[c] = a0[c]; r1[c] = a1[c]; }  // unscaled z
        }
    }
}

// ---------------- P4: per-bucket counting sort -> CSR + dinv ----------------
__device__ void ph_bsort(const GP& p, int* smem) {
    int bid = blockIdx.x, t = threadIdx.x;
    if (bid >= NB) return;
    int* cnt = smem; int* s = smem + BNODES; int* ofs = smem + 2 * BNODES;
    if (t < BNODES) cnt[t] = 0;
    __syncthreads();
    int beg = p.S[bid * NT];
    int end = (bid + 1 < NB) ? p.S[(bid + 1) * NT] : EE;
    for (int e = beg + t; e < end; e += BT)
        atomicAdd(&cnt[__builtin_nontemporal_load(&p.ebuf[e]) & (BNODES - 1)], 1);
    __syncthreads();
    int v = 0;
    if (t < BNODES) { v = cnt[t]; s[t] = v; }
    __syncthreads();
    for (int off = 1; off < BNODES; off <<= 1) {
        int u = 0;
        if (t < BNODES && t >= off) u = s[t - off];
        __syncthreads();
        if (t < BNODES) s[t] += u;
        __syncthreads();
    }
    if (t < BNODES) {
        int n = (bid << BSH) + t;
        if (n < NN) {
            p.dinv[n] = rsqrtf((float)(v + 1));   // +1 self loop
            p.rowptr[n] = beg + s[t];             // inclusive end
        }
        ofs[t] = beg + s[t] - v;
    }
    __syncthreads();
    for (int e = beg + t; e < end; e += BT) {
        unsigned pk = __builtin_nontemporal_load(&p.ebuf[e]);
        int pos = atomicAdd(&ofs[pk & (BNODES - 1)], 1);
        p.srcIdx[pos] = (int)(pk >> BSH);
    }
}

// ---------------- P5/6/7: gather rounds ----------------
// MODE 0: src = unscaled z, weight each edge by dinv[s], prescale out by dinv[n]
// MODE 1: src pre-scaled, prescale out. MODE 2: final, write y raw.
template <int MODE>
__device__ void ph_gather(const GP& p, const float* src, float* dst, int coff) {
    for (int gid = blockIdx.x * BT + threadIdx.x; gid < NN * LPN; gid += GRID * BT) {
        int n = gid >> 2, l = gid & 3;
        int beg = (n == 0) ? 0 : p.rowptr[n - 1];
        int end = p.rowptr[n];
        float acc[CO];
#pragma unroll
        for (int c = 0; c < CO; ++c) acc[c] = 0.f;
        for (int e = beg + l; e < end; e += LPN) {
            int s = __builtin_nontemporal_load(&p.srcIdx[e]);
            const float* sp = src + (size_t)s * PADF;
            float4 a = ((const float4*)sp)[0];
            float4 b = ((const float4*)sp)[1];
            float2 c2 = ((const float2*)(sp + 8))[0];
            if (MODE == 0) {
                float w = p.dinv[s];
                acc[0] += w * a.x; acc[1] += w * a.y; acc[2] += w * a.z; acc[3] += w * a.w;
                acc[4] += w * b.x; acc[5] += w * b.y; acc[6] += w * b.z; acc[7] += w * b.w;
                acc[8] += w * c2.x; acc[9] += w * c2.y;
            } else {
                acc[0] += a.x; acc[1] += a.y; acc[2] += a.z; acc[3] += a.w;
                acc[4] += b.x; acc[5] += b.y; acc[6] += b.z; acc[7] += b.w;
                acc[8] += c2.x; acc[9] += c2.y;
            }
        }
#pragma unroll
        for (int m = 1; m < LPN; m <<= 1) {
#pragma unroll
            for (int c = 0; c < CO; ++c) acc[c] += __shfl_xor(acc[c], m, 64);
        }
        if (l == 0) {
            float di = p.dinv[n];
            const float* selfp = src + (size_t)n * PADF;
            float4 sa = ((const float4*)selfp)[0];
            float4 sb = ((const float4*)selfp)[1];
            float2 sc = ((const float2*)(selfp + 8))[0];
            float self[CO] = {sa.x, sa.y, sa.z, sa.w, sb.x, sb.y, sb.z, sb.w, sc.x, sc.y};
            float o[CO];
#pragma unroll
            for (int c = 0; c < CO; ++c) {
                float sv = (MODE == 0) ? di * self[c] : self[c];
                float y = di * (acc[c] + sv) + p.cvec[coff + c];
                o[c] = (MODE == 2) ? y : y * di;
            }
            float* dp = dst + (size_t)n * PADF;
            ((float4*)dp)[0] = make_float4(o[0], o[1], o[2], o[3]);
            ((float4*)dp)[1] = make_float4(o[4], o[5], o[6], o[7]);
            ((float2*)(dp + 8))[0] = make_float2(o[8], o[9]);
        }
    }
}

// ---------------- P8: mean-pool per graph + bl ----------------
__device__ void ph_pool(const GP& p) {
    int t = threadIdx.x;
    for (int g = blockIdx.x * (BT / 64) + (t >> 6); g < GG; g += GRID * (BT / 64)) {
        int beg = p.gstart[g], end = p.gstart[g + 1];
        int l = t & 63;
        float acc[CO];
#pragma unroll
        for (int c = 0; c < CO; ++c) acc[c] = 0.f;
        for (int n = beg + l; n < end; n += 64) {
            const float* sp = p.bbuf + (size_t)n * PADF;
            float4 a = ((const float4*)sp)[0];
            float4 b = ((const float4*)sp)[1];
            float2 c2 = ((const float2*)(sp + 8))[0];
            acc[0] += a.x; acc[1] += a.y; acc[2] += a.z; acc[3] += a.w;
            acc[4] += b.x; acc[5] += b.y; acc[6] += b.z; acc[7] += b.w;
            acc[8] += c2.x; acc[9] += c2.y;
        }
#pragma unroll
        for (int m = 1; m < 64; m <<= 1) {
#pragma unroll
            for (int c = 0; c < CO; ++c) acc[c] += __shfl_xor(acc[c], m, 64);
        }
        if (l == 0) {
            float cf = fmaxf((float)(end - beg), 1.f);
#pragma unroll
            for (int c = 0; c < CO; ++c) p.out[(size_t)g * CO + c] = acc[c] / cf + p.bl[c];
        }
    }
}

// ---------------- cooperative mega-kernel ----------------
__global__ __launch_bounds__(BT, 6) void k_mega(GP p) {
    cg::grid_group grid = cg::this_grid();
    __shared__ int smem[1344];   // 5376 B, aliased per phase
    ph_front(p, smem);      grid.sync();
    ph_scanA(p, smem);      grid.sync();
    ph_scanC(p, smem);      grid.sync();
    ph_scatter_xw(p, smem); grid.sync();
    ph_bsort(p, smem);      grid.sync();
    ph_gather<0>(p, p.as_, p.bbuf, 0);      grid.sync();
    ph_gather<1>(p, p.bbuf, p.as_, CO);     grid.sync();
    ph_gather<2>(p, p.as_, p.bbuf, 2 * CO); grid.sync();
    ph_pool(p);
}

// ---------------- non-cooperative fallback wrappers (same phases) ----------------
__global__ __launch_bounds__(BT) void k_ph0(GP p) { __shared__ int smem[1344]; ph_front(p, smem); }
__global__ __launch_bounds__(BT) void k_ph1(GP p) { __shared__ int smem[1344]; ph_scanA(p, smem); }
__global__ __launch_bounds__(BT) void k_ph2(GP p) { __shared__ int smem[1344]; ph_scanC(p, smem); }
__global__ __launch_bounds__(BT) void k_ph3(GP p) { __shared__ int smem[1344]; ph_scatter_xw(p, smem); }
__global__ __launch_bounds__(BT) void k_ph4(GP p) { __shared__ int smem[1344]; ph_bsort(p, smem); }
__global__ __launch_bounds__(BT) void k_ph5(GP p) { ph_gather<0>(p, p.as_, p.bbuf, 0); }
__global__ __launch_bounds__(BT) void k_ph6(GP p) { ph_gather<1>(p, p.bbuf, p.as_, CO); }
__global__ __launch_bounds__(BT) void k_ph7(GP p) { ph_gather<2>(p, p.as_, p.bbuf, 2 * CO); }
__global__ __launch_bounds__(BT) void k_ph8(GP p) { ph_pool(p); }

extern "C" void kernel_launch(void* const* d_in, const int* in_sizes, int n_in,
                              void* d_out, int out_size, void* d_ws, size_t ws_size,
                              hipStream_t stream) {
    GP p;
    p.x     = (const float*)d_in[0];
    const int* ei = (const int*)d_in[1];
    p.row   = ei;            // edge_index[0]
    p.col   = ei + EE;       // edge_index[1]
    p.batch = (const int*)d_in[2];
    p.W1 = (const float*)d_in[3];  p.b1 = (const float*)d_in[4];
    p.W2 = (const float*)d_in[5];  p.b2 = (const float*)d_in[6];
    p.W3 = (const float*)d_in[7];  p.b3 = (const float*)d_in[8];
    p.Wl = (const float*)d_in[9];  p.bl = (const float*)d_in[10];
    p.out = (float*)d_out;

    float* ws = (float*)d_ws;
    size_t off = 0;
    auto alloc = [&](size_t elems) { size_t cur = off; off += (elems + 63) & ~(size_t)63; return cur; };
    p.Wf     = ws + alloc(DI * CO);
    p.cvec   = ws + alloc(3 * CO);
    p.dinv   = ws + alloc(NN);
    p.S      = (int*)(ws + alloc(SN));
    p.bsum   = (int*)(ws + alloc(NSB + 64));
    p.ebuf   = (unsigned*)(ws + alloc(EE));
    p.srcIdx = (int*)(ws + alloc(EE));
    p.rowptr = (int*)(ws + alloc(NN));
    p.as_    = ws + alloc((size_t)NN * PADF);
    p.bbuf   = ws + alloc((size_t)NN * PADF);
    p.gstart = (int*)(ws + alloc(GG + 1));
    (void)ws_size; (void)in_sizes; (void)n_in; (void)out_size;

    void* args[] = { &p };
    hipError_t err = hipLaunchCooperativeKernel((const void*)k_mega, dim3(GRID), dim3(BT),
                                                args, 0, stream);
    if (err != hipSuccess) {
        (void)hipGetLastError();   // clear sticky error; fall back to phase kernels
        hipLaunchKernelGGL(k_ph0, dim3(GRID), dim3(BT), 0, stream, p);
        hipLaunchKernelGGL(k_ph1, dim3(GRID), dim3(BT), 0, stream, p);
        hipLaunchKernelGGL(k_ph2, dim3(GRID), dim3(BT), 0, stream, p);
        hipLaunchKernelGGL(k_ph3, dim3(GRID), dim3(BT), 0, stream, p);
        hipLaunchKernelGGL(k_ph4, dim3(GRID), dim3(BT), 0, stream, p);
        hipLaunchKernelGGL(k_ph5, dim3(GRID), dim3(BT), 0, stream, p);
        hipLaunchKernelGGL(k_ph6, dim3(GRID), dim3(BT), 0, stream, p);
        hipLaunchKernelGGL(k_ph7, dim3(GRID), dim3(BT), 0, stream, p);
        hipLaunchKernelGGL(k_ph8, dim3(GRID), dim3(BT), 0, stream, p);
    }
}

// Round 12
// 288.782 us; speedup vs baseline: 6.0807x; 6.0807x over previous
//
#include <hip/hip_runtime.h>

#define NN 100000
#define EE 1600000
#define DI 128
#define HH 64
#define CO 10
#define PADF 16                             // floats per staged row (64B line)
#define GG 1024
#define BSH 7
#define BNODES 128
#define NB ((NN + BNODES - 1) / BNODES)     // 782
#define TILE 4096
#define NT ((EE + TILE - 1) / TILE)         // 391
#define SN (NB * NT)
#define SCB 1024
#define NSB ((SN + SCB - 1) / SCB)          // 299
#define LPN 4
#define BT 256

// ---- fused front: blocks [0,NT) bucket-histogram; block NT collapsed weights; rest gstart ----
__global__ __launch_bounds__(256) void k_front(const int* __restrict__ col,
                                               const float* __restrict__ W1, const float* __restrict__ W2,
                                               const float* __restrict__ W3, const float* __restrict__ Wl,
                                               const float* __restrict__ b1, const float* __restrict__ b2,
                                               const float* __restrict__ b3,
                                               const int* __restrict__ batch,
                                               int* __restrict__ cnt, float* __restrict__ Wf,
                                               float* __restrict__ cvec, int* __restrict__ gstart) {
    __shared__ float smem[1280];
    int bid = blockIdx.x, t = threadIdx.x;
    if (bid < NT) {
        int* h = (int*)smem;
        for (int i = t; i < NB; i += 256) h[i] = 0;
        __syncthreads();
        int base = bid * TILE, end = min(base + TILE, EE);
        for (int e = base + t; e < end; e += 256)
            atomicAdd(&h[__builtin_nontemporal_load(&col[e]) >> BSH], 1);
        __syncthreads();
        for (int i = t; i < NB; i += 256) cnt[i * NT + bid] = h[i];
    } else if (bid == NT) {
        float* M3l = smem;           // 640
        float* M23l = smem + 640;    // 640
        for (int i = t; i < HH * CO; i += 256) {
            int r = i / CO, c = i % CO; float s = 0.f;
            for (int k = 0; k < HH; ++k) s += W3[r * HH + k] * Wl[k * CO + c];
            M3l[i] = s;
        }
        __syncthreads();
        for (int i = t; i < HH * CO; i += 256) {
            int r = i / CO, c = i % CO; float s = 0.f;
            for (int k = 0; k < HH; ++k) s += W2[r * HH + k] * M3l[k * CO + c];
            M23l[i] = s;
        }
        __syncthreads();
        for (int i = t; i < DI * CO; i += 256) {
            int r = i / CO, c = i % CO; float s = 0.f;
            for (int k = 0; k < HH; ++k) s += W1[r * HH + k] * M23l[k * CO + c];
            Wf[i] = s;
        }
        if (t < CO) {
            float s1 = 0.f, s2 = 0.f, s3 = 0.f;
            for (int k = 0; k < HH; ++k) {
                s1 += b1[k] * M23l[k * CO + t];
                s2 += b2[k] * M3l[k * CO + t];
                s3 += b3[k] * Wl[k * CO + t];
            }
            cvec[t] = s1; cvec[CO + t] = s2; cvec[2 * CO + t] = s3;
        }
    } else {
        int g = (bid - NT - 1) * 256 + t;
        if (g <= GG) {
            int lo = 0, hi = NN;
            while (lo < hi) { int mid = (lo + hi) >> 1; if (batch[mid] < g) lo = mid + 1; else hi = mid; }
            gstart[g] = lo;
        }
    }
}

// ---------------- scanA: per-block exclusive scan, block totals to bsum ----------------
__global__ __launch_bounds__(SCB) void k_scanA(int* __restrict__ a, int* __restrict__ bsum) {
    __shared__ int s[SCB];
    int t = threadIdx.x, idx = blockIdx.x * SCB + t;
    int v = (idx < SN) ? a[idx] : 0;
    s[t] = v;
    __syncthreads();
    for (int off = 1; off < SCB; off <<= 1) {
        int u = (t >= off) ? s[t - off] : 0;
        __syncthreads();
        s[t] += u;
        __syncthreads();
    }
    if (idx < SN) a[idx] = s[t] - v;
    if (t == SCB - 1) bsum[blockIdx.x] = s[t];
}
// ---------------- scanC: block offset = reduce(bsum[0..bid)) ; add ----------------
__global__ __launch_bounds__(SCB) void k_scanC(int* __restrict__ a, const int* __restrict__ bsum) {
    __shared__ int red[SCB];
    int t = threadIdx.x, bid = blockIdx.x;
    int partial = 0;
    for (int i = t; i < bid; i += SCB) partial += bsum[i];
    red[t] = partial;
    __syncthreads();
    for (int off = SCB / 2; off > 0; off >>= 1) {
        if (t < off) red[t] += red[t + off];
        __syncthreads();
    }
    int idx = bid * SCB + t;
    if (idx < SN) a[idx] += red[0];
}

// ---- merged: blocks [0,NT) scatter edges bucket-major; blocks [NT,2NT) xw (unscaled z) ----
__global__ __launch_bounds__(256) void k_sxw(const int* __restrict__ row, const int* __restrict__ col,
                                             const int* __restrict__ S, unsigned* __restrict__ ebuf,
                                             const float* __restrict__ x, const float* __restrict__ Wf,
                                             float* __restrict__ as_) {
    __shared__ float smf[DI * CO];
    int* smi = (int*)smf;
    int bid = blockIdx.x, t = threadIdx.x;
    if (bid < NT) {
        for (int i = t; i < NB; i += 256) smi[i] = S[i * NT + bid];
        __syncthreads();
        int base = bid * TILE, end = min(base + TILE, EE);
        for (int e = base + t; e < end; e += 256) {
            int c = __builtin_nontemporal_load(&col[e]);
            int r = __builtin_nontemporal_load(&row[e]);
            int pos = atomicAdd(&smi[c >> BSH], 1);
            ebuf[pos] = ((unsigned)r << BSH) | (unsigned)(c & (BNODES - 1));
        }
    } else {
        for (int i = t; i < DI * CO; i += 256) smf[i] = Wf[i];
        __syncthreads();
        int gid = (bid - NT) * 256 + t;
        if (gid >= NN) return;
        int pr = gid >> 1, c0 = (gid & 1) * 5;
        int n0 = 2 * pr, n1 = n0 + 1;
        float a0[5] = {0, 0, 0, 0, 0}, a1[5] = {0, 0, 0, 0, 0};
        const float4* x0 = (const float4*)(x + (size_t)n0 * DI);
        const float4* x1 = (const float4*)(x + (size_t)n1 * DI);
#pragma unroll 4
        for (int d4 = 0; d4 < DI / 4; ++d4) {
            float4 u = x0[d4], v = x1[d4];
            const float* w = &smf[d4 * 4 * CO + c0];
#pragma unroll
            for (int c = 0; c < 5; ++c) {
                float w0 = w[c], w1 = w[CO + c], w2 = w[2 * CO + c], w3 = w[3 * CO + c];
                a0[c] += u.x * w0 + u.y * w1 + u.z * w2 + u.w * w3;
                a1[c] += v.x * w0 + v.y * w1 + v.z * w2 + v.w * w3;
            }
        }
        float* r0 = as_ + (size_t)n0 * PADF + c0;
        float* r1 = as_ + (size_t)n1 * PADF + c0;
#pragma unroll
        for (int c = 0; c < 5; ++c) { r0[c] = a0[c]; r1[c] = a1[c]; }   // unscaled z
    }
}

// ---------------- per-bucket counting sort -> CSR + dinv (zero global atomics) ----------------
__global__ __launch_bounds__(256) void k_bsort(const unsigned* __restrict__ ebuf, const int* __restrict__ S,
                                               int* __restrict__ srcIdx, int* __restrict__ rowptr_end,
                                               float* __restrict__ dinv) {
    __shared__ int cnt[BNODES];
    __shared__ int s[BNODES];
    __shared__ int ofs[BNODES];
    int t = threadIdx.x;
    int b = blockIdx.x;
    if (t < BNODES) cnt[t] = 0;
    __syncthreads();
    int beg = S[b * NT];
    int end = (b + 1 < NB) ? S[(b + 1) * NT] : EE;
    for (int e = beg + t; e < end; e += 256)
        atomicAdd(&cnt[__builtin_nontemporal_load(&ebuf[e]) & (BNODES - 1)], 1);
    __syncthreads();
    int v = 0;
    if (t < BNODES) { v = cnt[t]; s[t] = v; }
    __syncthreads();
    for (int off = 1; off < BNODES; off <<= 1) {
        int u = 0;
        if (t < BNODES && t >= off) u = s[t - off];
        __syncthreads();
        if (t < BNODES) s[t] += u;
        __syncthreads();
    }
    if (t < BNODES) {
        int n = (b << BSH) + t;
        if (n < NN) {
            dinv[n] = rsqrtf((float)(v + 1));        // +1 self loop
            rowptr_end[n] = beg + s[t];              // inclusive end
        }
        ofs[t] = beg + s[t] - v;                     // exclusive start
    }
    __syncthreads();
    for (int e = beg + t; e < end; e += 256) {
        unsigned p = __builtin_nontemporal_load(&ebuf[e]);
        int pos = atomicAdd(&ofs[p & (BNODES - 1)], 1);
        srcIdx[pos] = (int)(p >> BSH);
    }
}

// ---------------- gather rounds ----------------
// MODE 0: src = unscaled z -> weight edges by dinv[s], self by dinv[n]; prescale out by dinv[n]
// MODE 1: src pre-scaled; prescale out. MODE 2: final, write y raw.
template <int MODE>
__global__ __launch_bounds__(256) void k_gather(const int* __restrict__ rowptr_end,
                                                const int* __restrict__ srcIdx,
                                                const float* __restrict__ src,
                                                const float* __restrict__ dinv,
                                                const float* __restrict__ cvec, int coff,
                                                float* __restrict__ dst) {
    int gid = blockIdx.x * 256 + threadIdx.x;
    int n = gid >> 2;
    int l = threadIdx.x & (LPN - 1);
    if (n >= NN) return;
    int beg = (n == 0) ? 0 : rowptr_end[n - 1];
    int end = rowptr_end[n];
    float acc[CO];
#pragma unroll
    for (int c = 0; c < CO; ++c) acc[c] = 0.f;
    for (int e = beg + l; e < end; e += LPN) {
        int s = __builtin_nontemporal_load(&srcIdx[e]);
        const float* sp = src + (size_t)s * PADF;
        float4 a = ((const float4*)sp)[0];
        float4 b = ((const float4*)sp)[1];
        float2 c2 = ((const float2*)(sp + 8))[0];
        if (MODE == 0) {
            float w = dinv[s];
            acc[0] += w * a.x; acc[1] += w * a.y; acc[2] += w * a.z; acc[3] += w * a.w;
            acc[4] += w * b.x; acc[5] += w * b.y; acc[6] += w * b.z; acc[7] += w * b.w;
            acc[8] += w * c2.x; acc[9] += w * c2.y;
        } else {
            acc[0] += a.x; acc[1] += a.y; acc[2] += a.z; acc[3] += a.w;
            acc[4] += b.x; acc[5] += b.y; acc[6] += b.z; acc[7] += b.w;
            acc[8] += c2.x; acc[9] += c2.y;
        }
    }
#pragma unroll
    for (int m = 1; m < LPN; m <<= 1) {
#pragma unroll
        for (int c = 0; c < CO; ++c) acc[c] += __shfl_xor(acc[c], m, 64);
    }
    if (l == 0) {
        float di = dinv[n];
        const float* selfp = src + (size_t)n * PADF;
        float4 sa = ((const float4*)selfp)[0];
        float4 sb = ((const float4*)selfp)[1];
        float2 sc = ((const float2*)(selfp + 8))[0];
        float self[CO] = {sa.x, sa.y, sa.z, sa.w, sb.x, sb.y, sb.z, sb.w, sc.x, sc.y};
        float o[CO];
#pragma unroll
        for (int c = 0; c < CO; ++c) {
            float sv = (MODE == 0) ? di * self[c] : self[c];
            float y = di * (acc[c] + sv) + cvec[coff + c];
            o[c] = (MODE == 2) ? y : y * di;
        }
        float* dp = dst + (size_t)n * PADF;
        ((float4*)dp)[0] = make_float4(o[0], o[1], o[2], o[3]);
        ((float4*)dp)[1] = make_float4(o[4], o[5], o[6], o[7]);
        ((float2*)(dp + 8))[0] = make_float2(o[8], o[9]);
    }
}

// ---------------- mean-pool per graph + bl; one wave per graph ----------------
__global__ __launch_bounds__(64) void k_pool(const float* __restrict__ h,
                                             const int* __restrict__ gstart,
                                             const float* __restrict__ bl,
                                             float* __restrict__ out) {
    int g = blockIdx.x;
    int beg = gstart[g], end = gstart[g + 1];
    int l = threadIdx.x;
    float acc[CO];
#pragma unroll
    for (int c = 0; c < CO; ++c) acc[c] = 0.f;
    for (int n = beg + l; n < end; n += 64) {
        const float* sp = h + (size_t)n * PADF;
        float4 a = ((const float4*)sp)[0];
        float4 b = ((const float4*)sp)[1];
        float2 c2 = ((const float2*)(sp + 8))[0];
        acc[0] += a.x; acc[1] += a.y; acc[2] += a.z; acc[3] += a.w;
        acc[4] += b.x; acc[5] += b.y; acc[6] += b.z; acc[7] += b.w;
        acc[8] += c2.x; acc[9] += c2.y;
    }
#pragma unroll
    for (int m = 1; m < 64; m <<= 1) {
#pragma unroll
        for (int c = 0; c < CO; ++c) acc[c] += __shfl_xor(acc[c], m, 64);
    }
    if (l == 0) {
        float cf = fmaxf((float)(end - beg), 1.f);
#pragma unroll
        for (int c = 0; c < CO; ++c) out[(size_t)g * CO + c] = acc[c] / cf + bl[c];
    }
}

extern "C" void kernel_launch(void* const* d_in, const int* in_sizes, int n_in,
                              void* d_out, int out_size, void* d_ws, size_t ws_size,
                              hipStream_t stream) {
    const float* x    = (const float*)d_in[0];
    const int*   ei   = (const int*)d_in[1];
    const int*   batch= (const int*)d_in[2];
    const float* W1   = (const float*)d_in[3];
    const float* b1   = (const float*)d_in[4];
    const float* W2   = (const float*)d_in[5];
    const float* b2   = (const float*)d_in[6];
    const float* W3   = (const float*)d_in[7];
    const float* b3   = (const float*)d_in[8];
    const float* Wl   = (const float*)d_in[9];
    const float* bl   = (const float*)d_in[10];
    float* out = (float*)d_out;

    const int* row = ei;        // edge_index[0]
    const int* col = ei + EE;   // edge_index[1]

    float* ws = (float*)d_ws;
    size_t off = 0;
    auto alloc = [&](size_t elems) { size_t cur = off; off += (elems + 63) & ~(size_t)63; return cur; };
    float*    Wf      = ws + alloc(DI * CO);
    float*    cvec    = ws + alloc(3 * CO);
    float*    dinv    = ws + alloc(NN);
    int*      S       = (int*)(ws + alloc(SN));
    int*      bsum    = (int*)(ws + alloc(NSB + 64));
    unsigned* ebuf    = (unsigned*)(ws + alloc(EE));
    int*      srcIdx  = (int*)(ws + alloc(EE));
    int*      rowptr  = (int*)(ws + alloc(NN));
    float*    as_     = ws + alloc((size_t)NN * PADF);
    float*    bbuf    = ws + alloc((size_t)NN * PADF);
    int*      gstart  = (int*)(ws + alloc(GG + 1));
    (void)ws_size; (void)in_sizes; (void)n_in; (void)out_size;

    int gNL = ((NN * LPN) + BT - 1) / BT;
    int gFront = NT + 1 + (GG + 1 + BT - 1) / BT;
    int gSxw = NT + (NN + BT - 1) / BT;

    hipLaunchKernelGGL(k_front,    dim3(gFront), dim3(BT), 0, stream,
                       col, W1, W2, W3, Wl, b1, b2, b3, batch, S, Wf, cvec, gstart);
    hipLaunchKernelGGL(k_scanA,    dim3(NSB), dim3(SCB), 0, stream, S, bsum);
    hipLaunchKernelGGL(k_scanC,    dim3(NSB), dim3(SCB), 0, stream, S, bsum);
    hipLaunchKernelGGL(k_sxw,      dim3(gSxw), dim3(BT), 0, stream, row, col, S, ebuf, x, Wf, as_);
    hipLaunchKernelGGL(k_bsort,    dim3(NB),  dim3(BT), 0, stream, ebuf, S, srcIdx, rowptr, dinv);

    hipLaunchKernelGGL((k_gather<0>), dim3(gNL), dim3(BT), 0, stream, rowptr, srcIdx, as_,  dinv, cvec, 0,      bbuf);
    hipLaunchKernelGGL((k_gather<1>), dim3(gNL), dim3(BT), 0, stream, rowptr, srcIdx, bbuf, dinv, cvec, CO,     as_);
    hipLaunchKernelGGL((k_gather<2>), dim3(gNL), dim3(BT), 0, stream, rowptr, srcIdx, as_,  dinv, cvec, 2 * CO, bbuf);

    hipLaunchKernelGGL(k_pool, dim3(GG), dim3(64), 0, stream, bbuf, gstart, bl, out);
}

// Round 13
// 271.128 us; speedup vs baseline: 6.4766x; 1.0651x over previous
//
#include <hip/hip_runtime.h>

#define NN 100000
#define EE 1600000
#define DI 128
#define HH 64
#define CO 10
#define PADF 16                             // floats per staged row (64B line)
#define GG 1024
#define BSH 7
#define BNODES 128
#define NB ((NN + BNODES - 1) / BNODES)     // 782
#define TILE 4096
#define NT ((EE + TILE - 1) / TILE)         // 391
#define SN (NB * NT)
#define SCB 1024
#define NSB ((SN + SCB - 1) / SCB)          // 299
#define BT 256

// ---- fused front: blocks [0,NT) bucket-histogram; block NT collapsed weights; rest gstart ----
__global__ __launch_bounds__(256) void k_front(const int* __restrict__ col,
                                               const float* __restrict__ W1, const float* __restrict__ W2,
                                               const float* __restrict__ W3, const float* __restrict__ Wl,
                                               const float* __restrict__ b1, const float* __restrict__ b2,
                                               const float* __restrict__ b3,
                                               const int* __restrict__ batch,
                                               int* __restrict__ cnt, float* __restrict__ Wf,
                                               float* __restrict__ cvec, int* __restrict__ gstart) {
    __shared__ float smem[1280];
    int bid = blockIdx.x, t = threadIdx.x;
    if (bid < NT) {
        int* h = (int*)smem;
        for (int i = t; i < NB; i += 256) h[i] = 0;
        __syncthreads();
        int base = bid * TILE, end = min(base + TILE, EE);
        for (int e = base + t; e < end; e += 256)
            atomicAdd(&h[__builtin_nontemporal_load(&col[e]) >> BSH], 1);
        __syncthreads();
        for (int i = t; i < NB; i += 256) cnt[i * NT + bid] = h[i];
    } else if (bid == NT) {
        float* M3l = smem;           // 640
        float* M23l = smem + 640;    // 640
        for (int i = t; i < HH * CO; i += 256) {
            int r = i / CO, c = i % CO; float s = 0.f;
            for (int k = 0; k < HH; ++k) s += W3[r * HH + k] * Wl[k * CO + c];
            M3l[i] = s;
        }
        __syncthreads();
        for (int i = t; i < HH * CO; i += 256) {
            int r = i / CO, c = i % CO; float s = 0.f;
            for (int k = 0; k < HH; ++k) s += W2[r * HH + k] * M3l[k * CO + c];
            M23l[i] = s;
        }
        __syncthreads();
        for (int i = t; i < DI * CO; i += 256) {
            int r = i / CO, c = i % CO; float s = 0.f;
            for (int k = 0; k < HH; ++k) s += W1[r * HH + k] * M23l[k * CO + c];
            Wf[i] = s;
        }
        if (t < CO) {
            float s1 = 0.f, s2 = 0.f, s3 = 0.f;
            for (int k = 0; k < HH; ++k) {
                s1 += b1[k] * M23l[k * CO + t];
                s2 += b2[k] * M3l[k * CO + t];
                s3 += b3[k] * Wl[k * CO + t];
            }
            cvec[t] = s1; cvec[CO + t] = s2; cvec[2 * CO + t] = s3;
        }
    } else {
        int g = (bid - NT - 1) * 256 + t;
        if (g <= GG) {
            int lo = 0, hi = NN;
            while (lo < hi) { int mid = (lo + hi) >> 1; if (batch[mid] < g) lo = mid + 1; else hi = mid; }
            gstart[g] = lo;
        }
    }
}

// ---------------- scanA: per-block exclusive scan, block totals to bsum ----------------
__global__ __launch_bounds__(SCB) void k_scanA(int* __restrict__ a, int* __restrict__ bsum) {
    __shared__ int s[SCB];
    int t = threadIdx.x, idx = blockIdx.x * SCB + t;
    int v = (idx < SN) ? a[idx] : 0;
    s[t] = v;
    __syncthreads();
    for (int off = 1; off < SCB; off <<= 1) {
        int u = (t >= off) ? s[t - off] : 0;
        __syncthreads();
        s[t] += u;
        __syncthreads();
    }
    if (idx < SN) a[idx] = s[t] - v;
    if (t == SCB - 1) bsum[blockIdx.x] = s[t];
}
// ---------------- scanC: block offset = reduce(bsum[0..bid)) ; add ----------------
__global__ __launch_bounds__(SCB) void k_scanC(int* __restrict__ a, const int* __restrict__ bsum) {
    __shared__ int red[SCB];
    int t = threadIdx.x, bid = blockIdx.x;
    int partial = 0;
    for (int i = t; i < bid; i += SCB) partial += bsum[i];
    red[t] = partial;
    __syncthreads();
    for (int off = SCB / 2; off > 0; off >>= 1) {
        if (t < off) red[t] += red[t + off];
        __syncthreads();
    }
    int idx = bid * SCB + t;
    if (idx < SN) a[idx] += red[0];
}

// ---- merged: blocks [0,NT) scatter edges bucket-major; blocks [NT,..) xw (unscaled z, zero pads) ----
__global__ __launch_bounds__(256) void k_sxw(const int* __restrict__ row, const int* __restrict__ col,
                                             const int* __restrict__ S, unsigned* __restrict__ ebuf,
                                             const float* __restrict__ x, const float* __restrict__ Wf,
                                             float* __restrict__ as_) {
    __shared__ float smf[DI * CO];
    int* smi = (int*)smf;
    int bid = blockIdx.x, t = threadIdx.x;
    if (bid < NT) {
        for (int i = t; i < NB; i += 256) smi[i] = S[i * NT + bid];
        __syncthreads();
        int base = bid * TILE, end = min(base + TILE, EE);
        for (int e = base + t; e < end; e += 256) {
            int c = __builtin_nontemporal_load(&col[e]);
            int r = __builtin_nontemporal_load(&row[e]);
            int pos = atomicAdd(&smi[c >> BSH], 1);
            ebuf[pos] = ((unsigned)r << BSH) | (unsigned)(c & (BNODES - 1));
        }
    } else {
        for (int i = t; i < DI * CO; i += 256) smf[i] = Wf[i];
        __syncthreads();
        int gid = (bid - NT) * 256 + t;
        if (gid >= NN) return;
        int pr = gid >> 1, c0 = (gid & 1) * 5;
        int n0 = 2 * pr, n1 = n0 + 1;
        float a0[5] = {0, 0, 0, 0, 0}, a1[5] = {0, 0, 0, 0, 0};
        const float4* x0 = (const float4*)(x + (size_t)n0 * DI);
        const float4* x1 = (const float4*)(x + (size_t)n1 * DI);
#pragma unroll 4
        for (int d4 = 0; d4 < DI / 4; ++d4) {
            float4 u = x0[d4], v = x1[d4];
            const float* w = &smf[d4 * 4 * CO + c0];
#pragma unroll
            for (int c = 0; c < 5; ++c) {
                float w0 = w[c], w1 = w[CO + c], w2 = w[2 * CO + c], w3 = w[3 * CO + c];
                a0[c] += u.x * w0 + u.y * w1 + u.z * w2 + u.w * w3;
                a1[c] += v.x * w0 + v.y * w1 + v.z * w2 + v.w * w3;
            }
        }
        float* r0 = as_ + (size_t)n0 * PADF + c0;
        float* r1 = as_ + (size_t)n1 * PADF + c0;
#pragma unroll
        for (int c = 0; c < 5; ++c) { r0[c] = a0[c]; r1[c] = a1[c]; }   // unscaled z
        if (c0) {  // zero pad channels [10,16) of both rows (quad-gather reads full 64B)
            float* p0 = as_ + (size_t)n0 * PADF;
            float* p1 = as_ + (size_t)n1 * PADF;
            ((float2*)(p0 + 10))[0] = make_float2(0.f, 0.f);
            ((float4*)(p0 + 12))[0] = make_float4(0.f, 0.f, 0.f, 0.f);
            ((float2*)(p1 + 10))[0] = make_float2(0.f, 0.f);
            ((float4*)(p1 + 12))[0] = make_float4(0.f, 0.f, 0.f, 0.f);
        }
    }
}

// ---------------- per-bucket counting sort -> CSR + dinv (zero global atomics) ----------------
__global__ __launch_bounds__(256) void k_bsort(const unsigned* __restrict__ ebuf, const int* __restrict__ S,
                                               int* __restrict__ srcIdx, int* __restrict__ rowptr_end,
                                               float* __restrict__ dinv) {
    __shared__ int cnt[BNODES];
    __shared__ int s[BNODES];
    __shared__ int ofs[BNODES];
    int t = threadIdx.x;
    int b = blockIdx.x;
    if (t < BNODES) cnt[t] = 0;
    __syncthreads();
    int beg = S[b * NT];
    int end = (b + 1 < NB) ? S[(b + 1) * NT] : EE;
    for (int e = beg + t; e < end; e += 256)
        atomicAdd(&cnt[__builtin_nontemporal_load(&ebuf[e]) & (BNODES - 1)], 1);
    __syncthreads();
    int v = 0;
    if (t < BNODES) { v = cnt[t]; s[t] = v; }
    __syncthreads();
    for (int off = 1; off < BNODES; off <<= 1) {
        int u = 0;
        if (t < BNODES && t >= off) u = s[t - off];
        __syncthreads();
        if (t < BNODES) s[t] += u;
        __syncthreads();
    }
    if (t < BNODES) {
        int n = (b << BSH) + t;
        if (n < NN) {
            dinv[n] = rsqrtf((float)(v + 1));        // +1 self loop
            rowptr_end[n] = beg + s[t];              // inclusive end
        }
        ofs[t] = beg + s[t] - v;                     // exclusive start
    }
    __syncthreads();
    for (int e = beg + t; e < end; e += 256) {
        unsigned p = __builtin_nontemporal_load(&ebuf[e]);
        int pos = atomicAdd(&ofs[p & (BNODES - 1)], 1);
        srcIdx[pos] = (int)(p >> BSH);
    }
}

// ---------------- gather rounds: channel-split quad (4 lanes/node, 4 channels/lane) ----------------
// MODE 0: src = unscaled z -> weight edges by dinv[s], self by dinv[n]; prescale out by dinv[n]
// MODE 1: src pre-scaled; prescale out. MODE 2: final, write y raw.
template <int MODE>
__global__ __launch_bounds__(256) void k_gather(const int* __restrict__ rowptr_end,
                                                const int* __restrict__ srcIdx,
                                                const float* __restrict__ src,
                                                const float* __restrict__ dinv,
                                                const float* __restrict__ cvec, int coff,
                                                float* __restrict__ dst) {
    int gid = blockIdx.x * 256 + threadIdx.x;
    int n = gid >> 2;
    int l = threadIdx.x & 3;
    if (n >= NN) return;
    int beg = (n == 0) ? 0 : rowptr_end[n - 1];
    int end = rowptr_end[n];
    float4 acc = make_float4(0.f, 0.f, 0.f, 0.f);
#pragma unroll 4
    for (int e = beg; e < end; ++e) {
        int s = srcIdx[e];
        float4 v = ((const float4*)(src + (size_t)s * PADF))[l];   // 4 lanes hit one 64B line
        if (MODE == 0) {
            float w = dinv[s];
            acc.x += w * v.x; acc.y += w * v.y; acc.z += w * v.z; acc.w += w * v.w;
        } else {
            acc.x += v.x; acc.y += v.y; acc.z += v.z; acc.w += v.w;
        }
    }
    float di = dinv[n];
    float4 sv = ((const float4*)(src + (size_t)n * PADF))[l];
    if (MODE == 0) { sv.x *= di; sv.y *= di; sv.z *= di; sv.w *= di; }
    float cv0, cv1, cv2, cv3;
    {
        int ch = 4 * l;
        cv0 = (ch + 0 < CO) ? cvec[coff + ch + 0] : 0.f;
        cv1 = (ch + 1 < CO) ? cvec[coff + ch + 1] : 0.f;
        cv2 = (ch + 2 < CO) ? cvec[coff + ch + 2] : 0.f;
        cv3 = (ch + 3 < CO) ? cvec[coff + ch + 3] : 0.f;
    }
    float4 o;
    o.x = di * (acc.x + sv.x) + cv0;
    o.y = di * (acc.y + sv.y) + cv1;
    o.z = di * (acc.z + sv.z) + cv2;
    o.w = di * (acc.w + sv.w) + cv3;
    if (MODE != 2) { o.x *= di; o.y *= di; o.z *= di; o.w *= di; }
    ((float4*)(dst + (size_t)n * PADF))[l] = o;                    // coalesced 64B per node
}

// ---------------- mean-pool per graph + bl; one wave per graph ----------------
__global__ __launch_bounds__(64) void k_pool(const float* __restrict__ h,
                                             const int* __restrict__ gstart,
                                             const float* __restrict__ bl,
                                             float* __restrict__ out) {
    int g = blockIdx.x;
    int beg = gstart[g], end = gstart[g + 1];
    int l = threadIdx.x;
    float acc[CO];
#pragma unroll
    for (int c = 0; c < CO; ++c) acc[c] = 0.f;
    for (int n = beg + l; n < end; n += 64) {
        const float* sp = h + (size_t)n * PADF;
        float4 a = ((const float4*)sp)[0];
        float4 b = ((const float4*)sp)[1];
        float2 c2 = ((const float2*)(sp + 8))[0];
        acc[0] += a.x; acc[1] += a.y; acc[2] += a.z; acc[3] += a.w;
        acc[4] += b.x; acc[5] += b.y; acc[6] += b.z; acc[7] += b.w;
        acc[8] += c2.x; acc[9] += c2.y;
    }
#pragma unroll
    for (int m = 1; m < 64; m <<= 1) {
#pragma unroll
        for (int c = 0; c < CO; ++c) acc[c] += __shfl_xor(acc[c], m, 64);
    }
    if (l == 0) {
        float cf = fmaxf((float)(end - beg), 1.f);
#pragma unroll
        for (int c = 0; c < CO; ++c) out[(size_t)g * CO + c] = acc[c] / cf + bl[c];
    }
}

extern "C" void kernel_launch(void* const* d_in, const int* in_sizes, int n_in,
                              void* d_out, int out_size, void* d_ws, size_t ws_size,
                              hipStream_t stream) {
    const float* x    = (const float*)d_in[0];
    const int*   ei   = (const int*)d_in[1];
    const int*   batch= (const int*)d_in[2];
    const float* W1   = (const float*)d_in[3];
    const float* b1   = (const float*)d_in[4];
    const float* W2   = (const float*)d_in[5];
    const float* b2   = (const float*)d_in[6];
    const float* W3   = (const float*)d_in[7];
    const float* b3   = (const float*)d_in[8];
    const float* Wl   = (const float*)d_in[9];
    const float* bl   = (const float*)d_in[10];
    float* out = (float*)d_out;

    const int* row = ei;        // edge_index[0]
    const int* col = ei + EE;   // edge_index[1]

    float* ws = (float*)d_ws;
    size_t off = 0;
    auto alloc = [&](size_t elems) { size_t cur = off; off += (elems + 63) & ~(size_t)63; return cur; };
    float*    Wf      = ws + alloc(DI * CO);
    float*    cvec    = ws + alloc(3 * CO);
    float*    dinv    = ws + alloc(NN);
    int*      S       = (int*)(ws + alloc(SN));
    int*      bsum    = (int*)(ws + alloc(NSB + 64));
    unsigned* ebuf    = (unsigned*)(ws + alloc(EE));
    int*      srcIdx  = (int*)(ws + alloc(EE));
    int*      rowptr  = (int*)(ws + alloc(NN));
    float*    as_     = ws + alloc((size_t)NN * PADF);
    float*    bbuf    = ws + alloc((size_t)NN * PADF);
    int*      gstart  = (int*)(ws + alloc(GG + 1));
    (void)ws_size; (void)in_sizes; (void)n_in; (void)out_size;

    int gNL = ((NN * 4) + BT - 1) / BT;
    int gFront = NT + 1 + (GG + 1 + BT - 1) / BT;
    int gSxw = NT + (NN + BT - 1) / BT;

    hipLaunchKernelGGL(k_front,    dim3(gFront), dim3(BT), 0, stream,
                       col, W1, W2, W3, Wl, b1, b2, b3, batch, S, Wf, cvec, gstart);
    hipLaunchKernelGGL(k_scanA,    dim3(NSB), dim3(SCB), 0, stream, S, bsum);
    hipLaunchKernelGGL(k_scanC,    dim3(NSB), dim3(SCB), 0, stream, S, bsum);
    hipLaunchKernelGGL(k_sxw,      dim3(gSxw), dim3(BT), 0, stream, row, col, S, ebuf, x, Wf, as_);
    hipLaunchKernelGGL(k_bsort,    dim3(NB),  dim3(BT), 0, stream, ebuf, S, srcIdx, rowptr, dinv);

    hipLaunchKernelGGL((k_gather<0>), dim3(gNL), dim3(BT), 0, stream, rowptr, srcIdx, as_,  dinv, cvec, 0,      bbuf);
    hipLaunchKernelGGL((k_gather<1>), dim3(gNL), dim3(BT), 0, stream, rowptr, srcIdx, bbuf, dinv, cvec, CO,     as_);
    hipLaunchKernelGGL((k_gather<2>), dim3(gNL), dim3(BT), 0, stream, rowptr, srcIdx, as_,  dinv, cvec, 2 * CO, bbuf);

    hipLaunchKernelGGL(k_pool, dim3(GG), dim3(64), 0, stream, bbuf, gstart, bl, out);
}

// Round 14
// 264.182 us; speedup vs baseline: 6.6469x; 1.0263x over previous
//
#include <hip/hip_runtime.h>

#define NN 100000
#define EE 1600000
#define DI 128
#define HH 64
#define CO 10
#define PADF 16                             // floats per staged row (64B line)
#define GG 1024
#define BSH 9                               // 512 nodes per bucket
#define BNODES (1 << BSH)
#define NB ((NN + BNODES - 1) / BNODES)     // 196
#define TILE 4096
#define NT ((EE + TILE - 1) / TILE)         // 391
#define SN (NB * NT)                        // 76,636
#define SCB 1024
#define NSB ((SN + SCB - 1) / SCB)          // 75
#define BT 256

// ---- fused front: blocks [0,NT) bucket-histogram; block NT collapsed weights; rest gstart ----
__global__ __launch_bounds__(256) void k_front(const int* __restrict__ col,
                                               const float* __restrict__ W1, const float* __restrict__ W2,
                                               const float* __restrict__ W3, const float* __restrict__ Wl,
                                               const float* __restrict__ b1, const float* __restrict__ b2,
                                               const float* __restrict__ b3,
                                               const int* __restrict__ batch,
                                               int* __restrict__ cnt, float* __restrict__ Wf,
                                               float* __restrict__ cvec, int* __restrict__ gstart) {
    __shared__ float smem[1280];
    int bid = blockIdx.x, t = threadIdx.x;
    if (bid < NT) {
        int* h = (int*)smem;
        for (int i = t; i < NB; i += 256) h[i] = 0;
        __syncthreads();
        int base = bid * TILE, end = min(base + TILE, EE);
        for (int e = base + t; e < end; e += 256)
            atomicAdd(&h[__builtin_nontemporal_load(&col[e]) >> BSH], 1);
        __syncthreads();
        for (int i = t; i < NB; i += 256) cnt[i * NT + bid] = h[i];
    } else if (bid == NT) {
        float* M3l = smem;           // 640
        float* M23l = smem + 640;    // 640
        for (int i = t; i < HH * CO; i += 256) {
            int r = i / CO, c = i % CO; float s = 0.f;
            for (int k = 0; k < HH; ++k) s += W3[r * HH + k] * Wl[k * CO + c];
            M3l[i] = s;
        }
        __syncthreads();
        for (int i = t; i < HH * CO; i += 256) {
            int r = i / CO, c = i % CO; float s = 0.f;
            for (int k = 0; k < HH; ++k) s += W2[r * HH + k] * M3l[k * CO + c];
            M23l[i] = s;
        }
        __syncthreads();
        for (int i = t; i < DI * CO; i += 256) {
            int r = i / CO, c = i % CO; float s = 0.f;
            for (int k = 0; k < HH; ++k) s += W1[r * HH + k] * M23l[k * CO + c];
            Wf[i] = s;
        }
        if (t < CO) {
            float s1 = 0.f, s2 = 0.f, s3 = 0.f;
            for (int k = 0; k < HH; ++k) {
                s1 += b1[k] * M23l[k * CO + t];
                s2 += b2[k] * M3l[k * CO + t];
                s3 += b3[k] * Wl[k * CO + t];
            }
            cvec[t] = s1; cvec[CO + t] = s2; cvec[2 * CO + t] = s3;
        }
    } else {
        int g = (bid - NT - 1) * 256 + t;
        if (g <= GG) {
            int lo = 0, hi = NN;
            while (lo < hi) { int mid = (lo + hi) >> 1; if (batch[mid] < g) lo = mid + 1; else hi = mid; }
            gstart[g] = lo;
        }
    }
}

// ---------------- scanA: per-block exclusive scan, block totals to bsum ----------------
__global__ __launch_bounds__(SCB) void k_scanA(int* __restrict__ a, int* __restrict__ bsum) {
    __shared__ int s[SCB];
    int t = threadIdx.x, idx = blockIdx.x * SCB + t;
    int v = (idx < SN) ? a[idx] : 0;
    s[t] = v;
    __syncthreads();
    for (int off = 1; off < SCB; off <<= 1) {
        int u = (t >= off) ? s[t - off] : 0;
        __syncthreads();
        s[t] += u;
        __syncthreads();
    }
    if (idx < SN) a[idx] = s[t] - v;
    if (t == SCB - 1) bsum[blockIdx.x] = s[t];
}
// ---------------- scanC: block offset = reduce(bsum[0..bid)) ; add ----------------
__global__ __launch_bounds__(SCB) void k_scanC(int* __restrict__ a, const int* __restrict__ bsum) {
    __shared__ int red[SCB];
    int t = threadIdx.x, bid = blockIdx.x;
    int partial = 0;
    for (int i = t; i < bid; i += SCB) partial += bsum[i];
    red[t] = partial;
    __syncthreads();
    for (int off = SCB / 2; off > 0; off >>= 1) {
        if (t < off) red[t] += red[t + off];
        __syncthreads();
    }
    int idx = bid * SCB + t;
    if (idx < SN) a[idx] += red[0];
}

// ---- merged: blocks [0,NT) scatter edges bucket-major; blocks [NT,..) xw (unscaled z, zero pads) ----
__global__ __launch_bounds__(256) void k_sxw(const int* __restrict__ row, const int* __restrict__ col,
                                             const int* __restrict__ S, unsigned* __restrict__ ebuf,
                                             const float* __restrict__ x, const float* __restrict__ Wf,
                                             float* __restrict__ as_) {
    __shared__ float smf[DI * CO];
    int* smi = (int*)smf;
    int bid = blockIdx.x, t = threadIdx.x;
    if (bid < NT) {
        for (int i = t; i < NB; i += 256) smi[i] = S[i * NT + bid];
        __syncthreads();
        int base = bid * TILE, end = min(base + TILE, EE);
        for (int e = base + t; e < end; e += 256) {
            int c = __builtin_nontemporal_load(&col[e]);
            int r = __builtin_nontemporal_load(&row[e]);
            int pos = atomicAdd(&smi[c >> BSH], 1);
            ebuf[pos] = ((unsigned)r << BSH) | (unsigned)(c & (BNODES - 1));
        }
    } else {
        for (int i = t; i < DI * CO; i += 256) smf[i] = Wf[i];
        __syncthreads();
        int gid = (bid - NT) * 256 + t;
        if (gid >= NN) return;
        int pr = gid >> 1, c0 = (gid & 1) * 5;
        int n0 = 2 * pr, n1 = n0 + 1;
        float a0[5] = {0, 0, 0, 0, 0}, a1[5] = {0, 0, 0, 0, 0};
        const float4* x0 = (const float4*)(x + (size_t)n0 * DI);
        const float4* x1 = (const float4*)(x + (size_t)n1 * DI);
#pragma unroll 4
        for (int d4 = 0; d4 < DI / 4; ++d4) {
            float4 u = x0[d4], v = x1[d4];
            const float* w = &smf[d4 * 4 * CO + c0];
#pragma unroll
            for (int c = 0; c < 5; ++c) {
                float w0 = w[c], w1 = w[CO + c], w2 = w[2 * CO + c], w3 = w[3 * CO + c];
                a0[c] += u.x * w0 + u.y * w1 + u.z * w2 + u.w * w3;
                a1[c] += v.x * w0 + v.y * w1 + v.z * w2 + v.w * w3;
            }
        }
        float* r0 = as_ + (size_t)n0 * PADF + c0;
        float* r1 = as_ + (size_t)n1 * PADF + c0;
#pragma unroll
        for (int c = 0; c < 5; ++c) { r0[c] = a0[c]; r1[c] = a1[c]; }   // unscaled z
        if (c0) {  // zero pad channels [10,16) of both rows (quad-gather reads full 64B)
            float* p0 = as_ + (size_t)n0 * PADF;
            float* p1 = as_ + (size_t)n1 * PADF;
            ((float2*)(p0 + 10))[0] = make_float2(0.f, 0.f);
            ((float4*)(p0 + 12))[0] = make_float4(0.f, 0.f, 0.f, 0.f);
            ((float2*)(p1 + 10))[0] = make_float2(0.f, 0.f);
            ((float4*)(p1 + 12))[0] = make_float4(0.f, 0.f, 0.f, 0.f);
        }
    }
}

// ------- per-bucket counting sort (512 bins, pair-scan) -> CSR + dinv (zero global atomics) -------
__global__ __launch_bounds__(256) void k_bsort(const unsigned* __restrict__ ebuf, const int* __restrict__ S,
                                               int* __restrict__ srcIdx, int* __restrict__ rowptr_end,
                                               float* __restrict__ dinv) {
    __shared__ int cnt[BNODES];
    __shared__ int sc[BT];
    __shared__ int ofs[BNODES];
    int t = threadIdx.x;
    int b = blockIdx.x;
    for (int i = t; i < BNODES; i += BT) cnt[i] = 0;
    __syncthreads();
    int beg = S[b * NT];
    int end = (b + 1 < NB) ? S[(b + 1) * NT] : EE;
    for (int e = beg + t; e < end; e += BT)
        atomicAdd(&cnt[__builtin_nontemporal_load(&ebuf[e]) & (BNODES - 1)], 1);
    __syncthreads();
    int v0 = cnt[2 * t], v1 = cnt[2 * t + 1];
    int pair = v0 + v1;
    sc[t] = pair;
    __syncthreads();
    for (int off = 1; off < BT; off <<= 1) {
        int u = (t >= off) ? sc[t - off] : 0;
        __syncthreads();
        sc[t] += u;
        __syncthreads();
    }
    int excl = sc[t] - pair;                     // exclusive prefix of pair (2t)
    {
        int n0 = (b << BSH) + 2 * t;
        int n1 = n0 + 1;
        if (n0 < NN) {
            dinv[n0] = rsqrtf((float)(v0 + 1));      // +1 self loop
            rowptr_end[n0] = beg + excl + v0;        // inclusive end
        }
        if (n1 < NN) {
            dinv[n1] = rsqrtf((float)(v1 + 1));
            rowptr_end[n1] = beg + excl + v0 + v1;
        }
        ofs[2 * t] = beg + excl;                     // exclusive starts
        ofs[2 * t + 1] = beg + excl + v0;
    }
    __syncthreads();
    for (int e = beg + t; e < end; e += BT) {
        unsigned p = __builtin_nontemporal_load(&ebuf[e]);
        int pos = atomicAdd(&ofs[p & (BNODES - 1)], 1);
        srcIdx[pos] = (int)(p >> BSH);
    }
}

// ---------------- gather rounds: channel-split quad (4 lanes/node, 4 channels/lane) ----------------
// MODE 0: src = unscaled z -> weight edges by dinv[s], self by dinv[n]; prescale out by dinv[n]
// MODE 1: src pre-scaled; prescale out. MODE 2: final, write y raw.
template <int MODE>
__global__ __launch_bounds__(256) void k_gather(const int* __restrict__ rowptr_end,
                                                const int* __restrict__ srcIdx,
                                                const float* __restrict__ src,
                                                const float* __restrict__ dinv,
                                                const float* __restrict__ cvec, int coff,
                                                float* __restrict__ dst) {
    int gid = blockIdx.x * 256 + threadIdx.x;
    int n = gid >> 2;
    int l = threadIdx.x & 3;
    if (n >= NN) return;
    int beg = (n == 0) ? 0 : rowptr_end[n - 1];
    int end = rowptr_end[n];
    float4 acc = make_float4(0.f, 0.f, 0.f, 0.f);
#pragma unroll 4
    for (int e = beg; e < end; ++e) {
        int s = srcIdx[e];
        float4 v = ((const float4*)(src + (size_t)s * PADF))[l];   // 4 lanes hit one 64B line
        if (MODE == 0) {
            float w = dinv[s];
            acc.x += w * v.x; acc.y += w * v.y; acc.z += w * v.z; acc.w += w * v.w;
        } else {
            acc.x += v.x; acc.y += v.y; acc.z += v.z; acc.w += v.w;
        }
    }
    float di = dinv[n];
    float4 sv = ((const float4*)(src + (size_t)n * PADF))[l];
    if (MODE == 0) { sv.x *= di; sv.y *= di; sv.z *= di; sv.w *= di; }
    float cv0, cv1, cv2, cv3;
    {
        int ch = 4 * l;
        cv0 = (ch + 0 < CO) ? cvec[coff + ch + 0] : 0.f;
        cv1 = (ch + 1 < CO) ? cvec[coff + ch + 1] : 0.f;
        cv2 = (ch + 2 < CO) ? cvec[coff + ch + 2] : 0.f;
        cv3 = (ch + 3 < CO) ? cvec[coff + ch + 3] : 0.f;
    }
    float4 o;
    o.x = di * (acc.x + sv.x) + cv0;
    o.y = di * (acc.y + sv.y) + cv1;
    o.z = di * (acc.z + sv.z) + cv2;
    o.w = di * (acc.w + sv.w) + cv3;
    if (MODE != 2) { o.x *= di; o.y *= di; o.z *= di; o.w *= di; }
    ((float4*)(dst + (size_t)n * PADF))[l] = o;                    // coalesced 64B per node
}

// ---------------- mean-pool per graph + bl; one wave per graph ----------------
__global__ __launch_bounds__(64) void k_pool(const float* __restrict__ h,
                                             const int* __restrict__ gstart,
                                             const float* __restrict__ bl,
                                             float* __restrict__ out) {
    int g = blockIdx.x;
    int beg = gstart[g], end = gstart[g + 1];
    int l = threadIdx.x;
    float acc[CO];
#pragma unroll
    for (int c = 0; c < CO; ++c) acc[c] = 0.f;
    for (int n = beg + l; n < end; n += 64) {
        const float* sp = h + (size_t)n * PADF;
        float4 a = ((const float4*)sp)[0];
        float4 b = ((const float4*)sp)[1];
        float2 c2 = ((const float2*)(sp + 8))[0];
        acc[0] += a.x; acc[1] += a.y; acc[2] += a.z; acc[3] += a.w;
        acc[4] += b.x; acc[5] += b.y; acc[6] += b.z; acc[7] += b.w;
        acc[8] += c2.x; acc[9] += c2.y;
    }
#pragma unroll
    for (int m = 1; m < 64; m <<= 1) {
#pragma unroll
        for (int c = 0; c < CO; ++c) acc[c] += __shfl_xor(acc[c], m, 64);
    }
    if (l == 0) {
        float cf = fmaxf((float)(end - beg), 1.f);
#pragma unroll
        for (int c = 0; c < CO; ++c) out[(size_t)g * CO + c] = acc[c] / cf + bl[c];
    }
}

extern "C" void kernel_launch(void* const* d_in, const int* in_sizes, int n_in,
                              void* d_out, int out_size, void* d_ws, size_t ws_size,
                              hipStream_t stream) {
    const float* x    = (const float*)d_in[0];
    const int*   ei   = (const int*)d_in[1];
    const int*   batch= (const int*)d_in[2];
    const float* W1   = (const float*)d_in[3];
    const float* b1   = (const float*)d_in[4];
    const float* W2   = (const float*)d_in[5];
    const float* b2   = (const float*)d_in[6];
    const float* W3   = (const float*)d_in[7];
    const float* b3   = (const float*)d_in[8];
    const float* Wl   = (const float*)d_in[9];
    const float* bl   = (const float*)d_in[10];
    float* out = (float*)d_out;

    const int* row = ei;        // edge_index[0]
    const int* col = ei + EE;   // edge_index[1]

    float* ws = (float*)d_ws;
    size_t off = 0;
    auto alloc = [&](size_t elems) { size_t cur = off; off += (elems + 63) & ~(size_t)63; return cur; };
    float*    Wf      = ws + alloc(DI * CO);
    float*    cvec    = ws + alloc(3 * CO);
    float*    dinv    = ws + alloc(NN);
    int*      S       = (int*)(ws + alloc(SN));
    int*      bsum    = (int*)(ws + alloc(NSB + 64));
    unsigned* ebuf    = (unsigned*)(ws + alloc(EE));
    int*      srcIdx  = (int*)(ws + alloc(EE));
    int*      rowptr  = (int*)(ws + alloc(NN));
    float*    as_     = ws + alloc((size_t)NN * PADF);
    float*    bbuf    = ws + alloc((size_t)NN * PADF);
    int*      gstart  = (int*)(ws + alloc(GG + 1));
    (void)ws_size; (void)in_sizes; (void)n_in; (void)out_size;

    int gNL = ((NN * 4) + BT - 1) / BT;
    int gFront = NT + 1 + (GG + 1 + BT - 1) / BT;
    int gSxw = NT + (NN + BT - 1) / BT;

    hipLaunchKernelGGL(k_front,    dim3(gFront), dim3(BT), 0, stream,
                       col, W1, W2, W3, Wl, b1, b2, b3, batch, S, Wf, cvec, gstart);
    hipLaunchKernelGGL(k_scanA,    dim3(NSB), dim3(SCB), 0, stream, S, bsum);
    hipLaunchKernelGGL(k_scanC,    dim3(NSB), dim3(SCB), 0, stream, S, bsum);
    hipLaunchKernelGGL(k_sxw,      dim3(gSxw), dim3(BT), 0, stream, row, col, S, ebuf, x, Wf, as_);
    hipLaunchKernelGGL(k_bsort,    dim3(NB),  dim3(BT), 0, stream, ebuf, S, srcIdx, rowptr, dinv);

    hipLaunchKernelGGL((k_gather<0>), dim3(gNL), dim3(BT), 0, stream, rowptr, srcIdx, as_,  dinv, cvec, 0,      bbuf);
    hipLaunchKernelGGL((k_gather<1>), dim3(gNL), dim3(BT), 0, stream, rowptr, srcIdx, bbuf, dinv, cvec, CO,     as_);
    hipLaunchKernelGGL((k_gather<2>), dim3(gNL), dim3(BT), 0, stream, rowptr, srcIdx, as_,  dinv, cvec, 2 * CO, bbuf);

    hipLaunchKernelGGL(k_pool, dim3(GG), dim3(64), 0, stream, bbuf, gstart, bl, out);
}